// Round 1
// baseline (838.069 us; speedup 1.0000x reference)
//
#include <hip/hip_runtime.h>

// ---- problem constants ----
// B=2, T=2048, TREF=512, C=768, H=12, D=64, L=T+TREF=2560

typedef __bf16 bf16x8 __attribute__((ext_vector_type(8)));
typedef float floatx4 __attribute__((ext_vector_type(4)));

__device__ __forceinline__ ushort f2bf(float f) {
  uint u = __builtin_bit_cast(uint, f);
  return (ushort)((u + 0x7FFFu + ((u >> 16) & 1u)) >> 16);
}

// ---------------- cast kernel: fp32 -> bf16 for x, ref_feat, 6 weights ----------------
// dst regions: xb[3145728] | refb[786432] | W[6][589824]
__global__ __launch_bounds__(256) void cast_all(
    const float* __restrict__ x, const float* __restrict__ rf,
    const float* __restrict__ w0, const float* __restrict__ w1,
    const float* __restrict__ w2, const float* __restrict__ w3,
    const float* __restrict__ w4, const float* __restrict__ w5,
    ushort* __restrict__ dst) {
  size_t i4 = ((size_t)blockIdx.x * 256 + threadIdx.x) * 4;
  const float* src;
  size_t off;
  if (i4 < 3145728) { src = x; off = i4; }
  else if (i4 < 3932160) { src = rf; off = i4 - 3145728; }
  else {
    size_t r = i4 - 3932160;
    if (r < 589824) { src = w0; off = r; }
    else if (r < 2 * 589824) { src = w1; off = r - 589824; }
    else if (r < 3 * 589824) { src = w2; off = r - 2 * 589824; }
    else if (r < 4 * 589824) { src = w3; off = r - 3 * 589824; }
    else if (r < 5 * 589824) { src = w4; off = r - 4 * 589824; }
    else { src = w5; off = r - 5 * 589824; }
  }
  float4 v = *(const float4*)(src + off);
  ushort4 o;
  o.x = f2bf(v.x); o.y = f2bf(v.y); o.z = f2bf(v.z); o.w = f2bf(v.w);
  *(ushort4*)(dst + i4) = o;
}

// ---------------- GEMM: C[M,768] = A[M,768] @ Bt[768,768]^T + bias ----------------
// Bt is row-major (N,K) == the nn.Linear weight W as given.
// MODE 0: out bf16 q-layout   [b][h][t][d]    (m = b*2048+t, n = h*64+d)
// MODE 1: out bf16 kv-self    [b][h][t][d] stride L=2560
// MODE 2: out bf16 kv-ref     [b][h][2048+r][d]  (m = b*512+r)
// MODE 3: out fp32 row-major  [m][n]
template <int MODE>
__global__ __launch_bounds__(256) void gemm768(
    const ushort* __restrict__ A, const ushort* __restrict__ Bt,
    const float* __restrict__ bias, void* __restrict__ outp) {
  const int bm = blockIdx.x, bn = blockIdx.y;
  const int tid = threadIdx.x;
  const int w = tid >> 6, lane = tid & 63, quad = lane >> 4, l16 = lane & 15;
  const int mw = (w >> 1) * 64, nw = (w & 1) * 64;

  __shared__ __align__(16) ushort As[128 * 32];
  __shared__ __align__(16) ushort Bs[128 * 32];

  floatx4 acc[4][4];
#pragma unroll
  for (int mt = 0; mt < 4; ++mt)
#pragma unroll
    for (int nt = 0; nt < 4; ++nt) acc[mt][nt] = (floatx4){0.f, 0.f, 0.f, 0.f};

  const ushort* Ab = A + (size_t)bm * 128 * 768;
  const ushort* Bb = Bt + (size_t)bn * 128 * 768;
  const int r0 = tid >> 2, kp = (tid & 3) * 8;
  const int r1 = r0 + 64;

#pragma unroll 1
  for (int kb = 0; kb < 24; ++kb) {
    const int k0 = kb * 32;
    uint4 av0 = *(const uint4*)(Ab + (size_t)r0 * 768 + k0 + kp);
    uint4 av1 = *(const uint4*)(Ab + (size_t)r1 * 768 + k0 + kp);
    uint4 bv0 = *(const uint4*)(Bb + (size_t)r0 * 768 + k0 + kp);
    uint4 bv1 = *(const uint4*)(Bb + (size_t)r1 * 768 + k0 + kp);
    __syncthreads();
    *(uint4*)&As[tid * 8] = av0;
    *(uint4*)&As[(tid + 256) * 8] = av1;
    *(uint4*)&Bs[tid * 8] = bv0;
    *(uint4*)&Bs[(tid + 256) * 8] = bv1;
    __syncthreads();
    bf16x8 af[4], bfr[4];
#pragma unroll
    for (int mt = 0; mt < 4; ++mt)
      af[mt] = *(const bf16x8*)&As[(mw + mt * 16 + l16) * 32 + quad * 8];
#pragma unroll
    for (int nt = 0; nt < 4; ++nt)
      bfr[nt] = *(const bf16x8*)&Bs[(nw + nt * 16 + l16) * 32 + quad * 8];
#pragma unroll
    for (int mt = 0; mt < 4; ++mt)
#pragma unroll
      for (int nt = 0; nt < 4; ++nt)
        acc[mt][nt] = __builtin_amdgcn_mfma_f32_16x16x32_bf16(af[mt], bfr[nt], acc[mt][nt], 0, 0, 0);
  }

#pragma unroll
  for (int nt = 0; nt < 4; ++nt) {
    const int n = bn * 128 + nw + nt * 16 + l16;
    const float bv = bias[n];
    const int hh = n >> 6, dd = n & 63;
#pragma unroll
    for (int mt = 0; mt < 4; ++mt)
#pragma unroll
      for (int i = 0; i < 4; ++i) {
        const int m = bm * 128 + mw + mt * 16 + quad * 4 + i;
        const float val = acc[mt][nt][i] + bv;
        if (MODE == 3) {
          ((float*)outp)[(size_t)m * 768 + n] = val;
        } else {
          size_t idx;
          if (MODE == 0) {
            const int b = m >> 11, t = m & 2047;
            idx = ((size_t)(b * 12 + hh) * 2048 + t) * 64 + dd;
          } else if (MODE == 1) {
            const int b = m >> 11, t = m & 2047;
            idx = ((size_t)(b * 12 + hh) * 2560 + t) * 64 + dd;
          } else {
            const int b = m >> 9, r = m & 511;
            idx = ((size_t)(b * 12 + hh) * 2560 + 2048 + r) * 64 + dd;
          }
          ((ushort*)outp)[idx] = f2bf(val);
        }
      }
  }
}

// ---------------- flash attention (transposed-scores layout) ----------------
// grid (B, T/64, H), 256 threads = 4 waves; wave w owns q-rows [w*16, w*16+16).
// Computes S^T = K·Q^T so each lane owns one q-column (l&15): softmax reduce is
// per-lane over 16 regs + shfl_xor(16,32); alpha-rescale is lane-uniform.
__global__ __launch_bounds__(256) void attn(
    const ushort* __restrict__ qb, const ushort* __restrict__ kb,
    const ushort* __restrict__ vb, const int* __restrict__ mask,
    const float* __restrict__ relp, ushort* __restrict__ yb) {
  const int b = blockIdx.x, qt = blockIdx.y, h = blockIdx.z;
  const int tid = threadIdx.x;
  const int w = tid >> 6, lane = tid & 63, quad = lane >> 4, l16 = lane & 15;

  __shared__ __align__(16) ushort Qs[64 * 72];       // [qrow][d], stride 72
  __shared__ __align__(16) ushort Ks[64 * 72];       // [key][d], stride 72
  __shared__ __align__(16) ushort Vs[64 * 64];       // [d][key'] xor-swizzled chunks
  __shared__ __align__(16) ushort Ps[4][16 * 72];    // per-wave P^T as [qr][key], stride 72

  // ---- stage Q (once) ----
  const ushort* qsrc = qb + ((size_t)(b * 12 + h) * 2048 + qt * 64) * 64;
#pragma unroll
  for (int c = 0; c < 2; ++c) {
    const int f = tid + c * 256;                     // chunk of 8 bf16
    *(uint4*)&Qs[(f >> 3) * 72 + (f & 7) * 8] = *(const uint4*)(qsrc + f * 8);
  }
  __syncthreads();
  bf16x8 bQ[2];
  bQ[0] = *(const bf16x8*)&Qs[(w * 16 + l16) * 72 + quad * 8];
  bQ[1] = *(const bf16x8*)&Qs[(w * 16 + l16) * 72 + 32 + quad * 8];

  floatx4 acc[4];
#pragma unroll
  for (int mt = 0; mt < 4; ++mt) acc[mt] = (floatx4){0.f, 0.f, 0.f, 0.f};
  float m_run = -__builtin_inff(), l_run = 0.f;

  const ushort* ksrc = kb + (size_t)(b * 12 + h) * 2560 * 64;
  const ushort* vsrc = vb + (size_t)(b * 12 + h) * 2560 * 64;
  const int qrow = qt * 64 + w * 16 + l16;
  const int* mrow = mask + (size_t)b * 2048 * 2048 + (size_t)qrow * 2048;
  const float* rrow = relp + (size_t)h * 2048 * 2048 + (size_t)qrow * 2048;

#pragma unroll 1
  for (int kt = 0; kt < 40; ++kt) {
    // ---- stage K tile [key][d] and V tile transposed [d][key'] ----
    const ushort* kt0 = ksrc + kt * 64 * 64;
    const ushort* vt0 = vsrc + kt * 64 * 64;
    uint4 kd[2], vd[2];
#pragma unroll
    for (int c = 0; c < 2; ++c) {
      const int f = tid + c * 256;
      kd[c] = *(const uint4*)(kt0 + f * 8);
      vd[c] = *(const uint4*)(vt0 + f * 8);
    }
    __syncthreads();  // previous tile's LDS reads done
#pragma unroll
    for (int c = 0; c < 2; ++c) {
      const int f = tid + c * 256;
      *(uint4*)&Ks[(f >> 3) * 72 + (f & 7) * 8] = kd[c];
      // V transpose-scatter with xor chunk swizzle: key' = (key&7) | (((key>>3)^(d>>3))<<3)
      const int key = f >> 3, d0 = (f & 7) * 8;
      const int cb = (((key >> 3) ^ (f & 7)) & 7) * 8 + (key & 7);
      uint vv[4] = {vd[c].x, vd[c].y, vd[c].z, vd[c].w};
#pragma unroll
      for (int u = 0; u < 4; ++u) {
        Vs[(d0 + 2 * u) * 64 + cb] = (ushort)(vv[u] & 0xffffu);
        Vs[(d0 + 2 * u + 1) * 64 + cb] = (ushort)(vv[u] >> 16);
      }
    }
    __syncthreads();

    // ---- S^T = K·Q^T : lane holds S^T[key = mt*16+quad*4+i][qr = l16] ----
    float s[16];
    {
      floatx4 st[4];
#pragma unroll
      for (int mt = 0; mt < 4; ++mt) st[mt] = (floatx4){0.f, 0.f, 0.f, 0.f};
#pragma unroll
      for (int kk = 0; kk < 2; ++kk) {
#pragma unroll
        for (int mt = 0; mt < 4; ++mt) {
          bf16x8 aK = *(const bf16x8*)&Ks[(mt * 16 + l16) * 72 + kk * 32 + quad * 8];
          st[mt] = __builtin_amdgcn_mfma_f32_16x16x32_bf16(aK, bQ[kk], st[mt], 0, 0, 0);
        }
      }
#pragma unroll
      for (int mt = 0; mt < 4; ++mt)
#pragma unroll
        for (int i = 0; i < 4; ++i) s[mt * 4 + i] = st[mt][i] * 0.125f;
    }

    // ---- bias: self keys only (kt<32): -inf where mask==1 else +rel_pos ----
    if (kt < 32) {
      const int kb0 = kt * 64 + quad * 4;
#pragma unroll
      for (int mt = 0; mt < 4; ++mt)
#pragma unroll
        for (int i = 0; i < 4; ++i) {
          const int off = kb0 + mt * 16 + i;
          const float rv = rrow[off];
          const int mv = mrow[off];
          const int j = mt * 4 + i;
          s[j] = mv ? -__builtin_inff() : s[j] + rv;
        }
    }

    // ---- online softmax over this tile's 64 keys (per q-column) ----
    float tm = s[0];
#pragma unroll
    for (int j = 1; j < 16; ++j) tm = fmaxf(tm, s[j]);
    tm = fmaxf(tm, __shfl_xor(tm, 16));
    tm = fmaxf(tm, __shfl_xor(tm, 32));
    const float mnew = fmaxf(m_run, tm);
    const float mref = (mnew == -__builtin_inff()) ? 0.f : mnew;
    const float alpha = (m_run == -__builtin_inff()) ? 0.f : __expf(m_run - mnew);
    float p[16], rs = 0.f;
#pragma unroll
    for (int j = 0; j < 16; ++j) { p[j] = __expf(s[j] - mref); rs += p[j]; }
    rs += __shfl_xor(rs, 16);
    rs += __shfl_xor(rs, 32);
    l_run = l_run * alpha + rs;
    m_run = mnew;
#pragma unroll
    for (int mt = 0; mt < 4; ++mt)
#pragma unroll
      for (int i = 0; i < 4; ++i) acc[mt][i] *= alpha;

    // ---- P^T -> LDS as Pt[qr][key] (pairs -> b32 writes, conflict-free) ----
    ushort* pw = &Ps[w][l16 * 72 + quad * 4];
#pragma unroll
    for (int mt = 0; mt < 4; ++mt) {
      const uint pk0 = (uint)f2bf(p[mt * 4 + 0]) | ((uint)f2bf(p[mt * 4 + 1]) << 16);
      const uint pk1 = (uint)f2bf(p[mt * 4 + 2]) | ((uint)f2bf(p[mt * 4 + 3]) << 16);
      *(uint*)&pw[mt * 16] = pk0;
      *(uint*)&pw[mt * 16 + 2] = pk1;
    }

    // ---- O^T += V^T · P^T ----
#pragma unroll
    for (int kk = 0; kk < 2; ++kk) {
      const bf16x8 bP = *(const bf16x8*)&Ps[w][l16 * 72 + kk * 32 + quad * 8];
#pragma unroll
      for (int mt = 0; mt < 4; ++mt) {
        const int dd = mt * 16 + l16;
        const int cs = (((kk * 4 + quad) ^ (dd >> 3)) & 7) * 8;
        const bf16x8 aV = *(const bf16x8*)&Vs[dd * 64 + cs];
        acc[mt] = __builtin_amdgcn_mfma_f32_16x16x32_bf16(aV, bP, acc[mt], 0, 0, 0);
      }
    }
  }

  // ---- epilogue: y[b][t][h*64+d] bf16 ----
  const float inv = 1.f / l_run;
  ushort* yrow = yb + ((size_t)b * 2048 + qt * 64 + w * 16 + l16) * 768 + h * 64;
#pragma unroll
  for (int mt = 0; mt < 4; ++mt)
#pragma unroll
    for (int i = 0; i < 4; ++i)
      yrow[mt * 16 + quad * 4 + i] = f2bf(acc[mt][i] * inv);
}

// ---------------- launch ----------------
extern "C" void kernel_launch(void* const* d_in, const int* in_sizes, int n_in,
                              void* d_out, int out_size, void* d_ws, size_t ws_size,
                              hipStream_t stream) {
  const float* x = (const float*)d_in[0];
  const int* mask = (const int*)d_in[1];
  const float* relp = (const float*)d_in[2];
  const float* ref = (const float*)d_in[3];
  const float* Wq = (const float*)d_in[4];
  const float* bq = (const float*)d_in[5];
  const float* Wk = (const float*)d_in[6];
  const float* bk = (const float*)d_in[7];
  const float* Wv = (const float*)d_in[8];
  const float* bv = (const float*)d_in[9];
  const float* Wrk = (const float*)d_in[10];
  const float* brk = (const float*)d_in[11];
  const float* Wrv = (const float*)d_in[12];
  const float* brv = (const float*)d_in[13];
  const float* Wo = (const float*)d_in[14];
  const float* bo = (const float*)d_in[15];

  ushort* xb = (ushort*)d_ws;                 // 3,145,728
  ushort* refb = xb + 3145728;                // 786,432
  ushort* wb = refb + 786432;                 // 6 * 589,824  (q,k,v,rk,rv,o)
  ushort* qbuf = wb + 6 * 589824;             // 3,145,728   [b][h][t][d]
  ushort* kbuf = qbuf + 3145728;              // 3,932,160   [b][h][key][d], L=2560
  ushort* vbuf = kbuf + 3932160;              // 3,932,160
  ushort* ybuf = vbuf + 3932160;              // 3,145,728   [b][t][c]

  cast_all<<<7296, 256, 0, stream>>>(x, ref, Wq, Wk, Wv, Wrk, Wrv, Wo, xb);

  gemm768<0><<<dim3(32, 6), 256, 0, stream>>>(xb, wb + 0 * 589824, bq, qbuf);
  gemm768<1><<<dim3(32, 6), 256, 0, stream>>>(xb, wb + 1 * 589824, bk, kbuf);
  gemm768<1><<<dim3(32, 6), 256, 0, stream>>>(xb, wb + 2 * 589824, bv, vbuf);
  gemm768<2><<<dim3(8, 6), 256, 0, stream>>>(refb, wb + 3 * 589824, brk, kbuf);
  gemm768<2><<<dim3(8, 6), 256, 0, stream>>>(refb, wb + 4 * 589824, brv, vbuf);

  attn<<<dim3(2, 32, 12), 256, 0, stream>>>(qbuf, kbuf, vbuf, mask, relp, ybuf);

  gemm768<3><<<dim3(32, 6), 256, 0, stream>>>(ybuf, wb + 5 * 589824, bo, d_out);
}

// Round 2
// 527.155 us; speedup vs baseline: 1.5898x; 1.5898x over previous
//
#include <hip/hip_runtime.h>

// ---- problem constants ----
// B=2, T=2048, TREF=512, C=768, H=12, D=64, L=T+TREF=2560

typedef __bf16 bf16x8 __attribute__((ext_vector_type(8)));
typedef float floatx4 __attribute__((ext_vector_type(4)));

__device__ __forceinline__ ushort f2bf(float f) {
  uint u = __builtin_bit_cast(uint, f);
  return (ushort)((u + 0x7FFFu + ((u >> 16) & 1u)) >> 16);
}

// ---------------- cast kernel: fp32 -> bf16 for x, ref_feat, 6 weights ----------------
// dst regions: xb[3145728] | refb[786432] | W[6][589824]
__global__ __launch_bounds__(256) void cast_all(
    const float* __restrict__ x, const float* __restrict__ rf,
    const float* __restrict__ w0, const float* __restrict__ w1,
    const float* __restrict__ w2, const float* __restrict__ w3,
    const float* __restrict__ w4, const float* __restrict__ w5,
    ushort* __restrict__ dst) {
  size_t i4 = ((size_t)blockIdx.x * 256 + threadIdx.x) * 4;
  const float* src;
  size_t off;
  if (i4 < 3145728) { src = x; off = i4; }
  else if (i4 < 3932160) { src = rf; off = i4 - 3145728; }
  else {
    size_t r = i4 - 3932160;
    if (r < 589824) { src = w0; off = r; }
    else if (r < 2 * 589824) { src = w1; off = r - 589824; }
    else if (r < 3 * 589824) { src = w2; off = r - 2 * 589824; }
    else if (r < 4 * 589824) { src = w3; off = r - 3 * 589824; }
    else if (r < 5 * 589824) { src = w4; off = r - 4 * 589824; }
    else { src = w5; off = r - 5 * 589824; }
  }
  float4 v = *(const float4*)(src + off);
  ushort4 o;
  o.x = f2bf(v.x); o.y = f2bf(v.y); o.z = f2bf(v.z); o.w = f2bf(v.w);
  *(ushort4*)(dst + i4) = o;
}

// ---------------- shared GEMM core: 128x128 tile, K=768, bf16 MFMA ----------------
__device__ __forceinline__ void gemm_core(
    const ushort* __restrict__ Ab, const ushort* __restrict__ Bb,
    ushort* As, ushort* Bs, int tid, int quad, int l16, int mw, int nw,
    floatx4 acc[4][4]) {
  const int r0 = tid >> 2, kp = (tid & 3) * 8;
  const int r1 = r0 + 64;
#pragma unroll 1
  for (int kb = 0; kb < 24; ++kb) {
    const int k0 = kb * 32;
    uint4 av0 = *(const uint4*)(Ab + (size_t)r0 * 768 + k0 + kp);
    uint4 av1 = *(const uint4*)(Ab + (size_t)r1 * 768 + k0 + kp);
    uint4 bv0 = *(const uint4*)(Bb + (size_t)r0 * 768 + k0 + kp);
    uint4 bv1 = *(const uint4*)(Bb + (size_t)r1 * 768 + k0 + kp);
    __syncthreads();
    *(uint4*)&As[tid * 8] = av0;
    *(uint4*)&As[(tid + 256) * 8] = av1;
    *(uint4*)&Bs[tid * 8] = bv0;
    *(uint4*)&Bs[(tid + 256) * 8] = bv1;
    __syncthreads();
    bf16x8 af[4], bfr[4];
#pragma unroll
    for (int mt = 0; mt < 4; ++mt)
      af[mt] = *(const bf16x8*)&As[(mw + mt * 16 + l16) * 32 + quad * 8];
#pragma unroll
    for (int nt = 0; nt < 4; ++nt)
      bfr[nt] = *(const bf16x8*)&Bs[(nw + nt * 16 + l16) * 32 + quad * 8];
#pragma unroll
    for (int mt = 0; mt < 4; ++mt)
#pragma unroll
      for (int nt = 0; nt < 4; ++nt)
        acc[mt][nt] = __builtin_amdgcn_mfma_f32_16x16x32_bf16(af[mt], bfr[nt], acc[mt][nt], 0, 0, 0);
  }
}

// ---------------- fused projection GEMMs ----------------
// REF=0: A=xb [4096x768], W=[2304x768] (Wq|Wk|Wv), grid (32,18); sections q,k,v
// REF=1: A=refb [1024x768], W=[1536x768] (Wrk|Wrv), grid (8,12); sections rk,rv
template <int REF>
__global__ __launch_bounds__(256) void gemm_fused(
    const ushort* __restrict__ A, const ushort* __restrict__ W,
    const float* __restrict__ bA, const float* __restrict__ bB,
    const float* __restrict__ bC,
    ushort* __restrict__ oA, ushort* __restrict__ oB, ushort* __restrict__ oC) {
  const int bm = blockIdx.x, bn = blockIdx.y;
  const int tid = threadIdx.x;
  const int w = tid >> 6, lane = tid & 63, quad = lane >> 4, l16 = lane & 15;
  const int mw = (w >> 1) * 64, nw = (w & 1) * 64;

  __shared__ __align__(16) ushort As[128 * 32];
  __shared__ __align__(16) ushort Bs[128 * 32];

  floatx4 acc[4][4];
#pragma unroll
  for (int mt = 0; mt < 4; ++mt)
#pragma unroll
    for (int nt = 0; nt < 4; ++nt) acc[mt][nt] = (floatx4){0.f, 0.f, 0.f, 0.f};

  gemm_core(A + (size_t)bm * 128 * 768, W + (size_t)bn * 128 * 768,
            As, Bs, tid, quad, l16, mw, nw, acc);

  const int sec = bn / 6;
  const float* bp = sec == 0 ? bA : sec == 1 ? bB : bC;
  ushort* op = sec == 0 ? oA : sec == 1 ? oB : oC;
  const bool qlay = (REF == 0 && sec == 0);
#pragma unroll
  for (int nt = 0; nt < 4; ++nt) {
    const int nloc = (bn - sec * 6) * 128 + nw + nt * 16 + l16;
    const float bv = bp[nloc];
    const int hh = nloc >> 6, dd = nloc & 63;
#pragma unroll
    for (int mt = 0; mt < 4; ++mt)
#pragma unroll
      for (int i = 0; i < 4; ++i) {
        const int m = bm * 128 + mw + mt * 16 + quad * 4 + i;
        int bb, tt;
        if (REF == 0) { bb = m >> 11; tt = m & 2047; }
        else { bb = m >> 9; tt = (m & 511) + 2048; }
        const size_t idx = qlay ? (((size_t)(bb * 12 + hh) * 2048 + tt) * 64 + dd)
                                : (((size_t)(bb * 12 + hh) * 2560 + tt) * 64 + dd);
        op[idx] = f2bf(acc[mt][nt][i] + bv);
      }
  }
}

// ---------------- output projection: fp32 out ----------------
__global__ __launch_bounds__(256) void gemm_out(
    const ushort* __restrict__ A, const ushort* __restrict__ W,
    const float* __restrict__ bias, float* __restrict__ out) {
  const int bm = blockIdx.x, bn = blockIdx.y;
  const int tid = threadIdx.x;
  const int w = tid >> 6, lane = tid & 63, quad = lane >> 4, l16 = lane & 15;
  const int mw = (w >> 1) * 64, nw = (w & 1) * 64;

  __shared__ __align__(16) ushort As[128 * 32];
  __shared__ __align__(16) ushort Bs[128 * 32];

  floatx4 acc[4][4];
#pragma unroll
  for (int mt = 0; mt < 4; ++mt)
#pragma unroll
    for (int nt = 0; nt < 4; ++nt) acc[mt][nt] = (floatx4){0.f, 0.f, 0.f, 0.f};

  gemm_core(A + (size_t)bm * 128 * 768, W + (size_t)bn * 128 * 768,
            As, Bs, tid, quad, l16, mw, nw, acc);

#pragma unroll
  for (int nt = 0; nt < 4; ++nt) {
    const int n = bn * 128 + nw + nt * 16 + l16;
    const float bv = bias[n];
#pragma unroll
    for (int mt = 0; mt < 4; ++mt)
#pragma unroll
      for (int i = 0; i < 4; ++i) {
        const int m = bm * 128 + mw + mt * 16 + quad * 4 + i;
        out[(size_t)m * 768 + n] = acc[mt][nt][i] + bv;
      }
  }
}

// ---------------- flash attention, v2: LDS bias staging + reg prefetch ----------------
// grid (B, T/64, H), 256 threads = 4 waves; wave w owns q-rows [w*16, w*16+16).
// S^T = K·Q^T so each lane owns one q-column (l16). Bias tile (mask ? -inf :
// rel_pos) is staged coalesced into LDS [64][65] fp32 (pad-1: writes 2-way=free).
// Tile k+1's K/V/mask/rel are loaded into regs while tile k computes.
__global__ __launch_bounds__(256, 3) void attn(
    const ushort* __restrict__ qb, const ushort* __restrict__ kb,
    const ushort* __restrict__ vb, const int* __restrict__ mask,
    const float* __restrict__ relp, ushort* __restrict__ yb) {
  const int b = blockIdx.x, qt = blockIdx.y, h = blockIdx.z;
  const int tid = threadIdx.x;
  const int w = tid >> 6, lane = tid & 63, quad = lane >> 4, l16 = lane & 15;

  __shared__ __align__(16) ushort Qs[64 * 72];     // [qrow][d], stride 72
  __shared__ __align__(16) ushort Ks[64 * 72];     // [key][d], stride 72
  __shared__ __align__(16) ushort Vs[64 * 64];     // [d][key'] xor-swizzled chunks
  __shared__ __align__(16) ushort Ps[4][16 * 72];  // per-wave P^T [qr][key]
  __shared__ float BiasS[64 * 65];                 // [qrow_local][key] fp32, pad 1

  const ushort* qsrc = qb + ((size_t)(b * 12 + h) * 2048 + qt * 64) * 64;
  const ushort* ksrc = kb + (size_t)(b * 12 + h) * 2560 * 64;
  const ushort* vsrc = vb + (size_t)(b * 12 + h) * 2560 * 64;
  const int* mbase = mask + ((size_t)b * 2048 + qt * 64) * 2048;
  const float* rbase = relp + ((size_t)h * 2048 + qt * 64) * 2048;

  // ---- stage Q ----
#pragma unroll
  for (int c = 0; c < 2; ++c) {
    const int f = tid + c * 256;  // chunk of 8 bf16
    *(uint4*)&Qs[(f >> 3) * 72 + (f & 7) * 8] = *(const uint4*)(qsrc + f * 8);
  }

  // ---- prefetch tile 0 into regs ----
  uint4 kd[2], vd[2];
  int4 md[4];
  float4 rd[4];
  {
    kd[0] = *(const uint4*)(ksrc + tid * 8);
    kd[1] = *(const uint4*)(ksrc + (tid + 256) * 8);
    vd[0] = *(const uint4*)(vsrc + tid * 8);
    vd[1] = *(const uint4*)(vsrc + (tid + 256) * 8);
#pragma unroll
    for (int p = 0; p < 4; ++p) {
      const int f2 = tid * 4 + p * 1024, row = f2 >> 6, col = f2 & 63;
      md[p] = *(const int4*)(mbase + (size_t)row * 2048 + col);
      rd[p] = *(const float4*)(rbase + (size_t)row * 2048 + col);
    }
  }
  __syncthreads();  // Qs staged

  // ---- write tile 0 to LDS ----
#pragma unroll
  for (int c = 0; c < 2; ++c) {
    const int f = tid + c * 256;
    *(uint4*)&Ks[(f >> 3) * 72 + (f & 7) * 8] = kd[c];
    const int key = f >> 3, d0 = (f & 7) * 8;
    const int cb = (((key >> 3) ^ (f & 7)) & 7) * 8 + (key & 7);
    uint vv[4] = {vd[c].x, vd[c].y, vd[c].z, vd[c].w};
#pragma unroll
    for (int u = 0; u < 4; ++u) {
      Vs[(d0 + 2 * u) * 64 + cb] = (ushort)(vv[u] & 0xffffu);
      Vs[(d0 + 2 * u + 1) * 64 + cb] = (ushort)(vv[u] >> 16);
    }
  }
#pragma unroll
  for (int p = 0; p < 4; ++p) {
    const int f2 = tid * 4 + p * 1024, row = f2 >> 6, col = f2 & 63;
    float* bsw = &BiasS[row * 65 + col];
    bsw[0] = md[p].x ? -__builtin_inff() : rd[p].x;
    bsw[1] = md[p].y ? -__builtin_inff() : rd[p].y;
    bsw[2] = md[p].z ? -__builtin_inff() : rd[p].z;
    bsw[3] = md[p].w ? -__builtin_inff() : rd[p].w;
  }

  bf16x8 bQ[2];
  bQ[0] = *(const bf16x8*)&Qs[(w * 16 + l16) * 72 + quad * 8];
  bQ[1] = *(const bf16x8*)&Qs[(w * 16 + l16) * 72 + 32 + quad * 8];

  floatx4 acc[4];
#pragma unroll
  for (int mt = 0; mt < 4; ++mt) acc[mt] = (floatx4){0.f, 0.f, 0.f, 0.f};
  float m_run = -__builtin_inff(), l_run = 0.f;

  __syncthreads();  // tile 0 LDS ready

#pragma unroll 1
  for (int kt = 0; kt < 40; ++kt) {
    const int ktn = kt + 1;
    // ---- prefetch tile kt+1 into regs (overlaps with compute below) ----
    if (ktn < 40) {
      const ushort* kt0 = ksrc + ktn * 4096;
      const ushort* vt0 = vsrc + ktn * 4096;
      kd[0] = *(const uint4*)(kt0 + tid * 8);
      kd[1] = *(const uint4*)(kt0 + (tid + 256) * 8);
      vd[0] = *(const uint4*)(vt0 + tid * 8);
      vd[1] = *(const uint4*)(vt0 + (tid + 256) * 8);
      if (ktn < 32) {
#pragma unroll
        for (int p = 0; p < 4; ++p) {
          const int f2 = tid * 4 + p * 1024, row = f2 >> 6, col = f2 & 63;
          md[p] = *(const int4*)(mbase + (size_t)row * 2048 + ktn * 64 + col);
          rd[p] = *(const float4*)(rbase + (size_t)row * 2048 + ktn * 64 + col);
        }
      }
    }

    // ---- S^T = K·Q^T : lane holds S^T[key = mt*16+quad*4+i][qr = l16] ----
    float s[16];
    {
      floatx4 st[4];
#pragma unroll
      for (int mt = 0; mt < 4; ++mt) st[mt] = (floatx4){0.f, 0.f, 0.f, 0.f};
#pragma unroll
      for (int kk = 0; kk < 2; ++kk) {
#pragma unroll
        for (int mt = 0; mt < 4; ++mt) {
          bf16x8 aK = *(const bf16x8*)&Ks[(mt * 16 + l16) * 72 + kk * 32 + quad * 8];
          st[mt] = __builtin_amdgcn_mfma_f32_16x16x32_bf16(aK, bQ[kk], st[mt], 0, 0, 0);
        }
      }
#pragma unroll
      for (int mt = 0; mt < 4; ++mt)
#pragma unroll
        for (int i = 0; i < 4; ++i) s[mt * 4 + i] = st[mt][i] * 0.125f;
    }

    // ---- bias from LDS: self keys only ----
    if (kt < 32) {
      const float* brow = &BiasS[(w * 16 + l16) * 65 + quad * 4];
#pragma unroll
      for (int mt = 0; mt < 4; ++mt)
#pragma unroll
        for (int i = 0; i < 4; ++i) s[mt * 4 + i] += brow[mt * 16 + i];
    }

    // ---- online softmax over this tile's 64 keys (per q-column) ----
    float tm = s[0];
#pragma unroll
    for (int j = 1; j < 16; ++j) tm = fmaxf(tm, s[j]);
    tm = fmaxf(tm, __shfl_xor(tm, 16));
    tm = fmaxf(tm, __shfl_xor(tm, 32));
    const float mnew = fmaxf(m_run, tm);
    const float mref = (mnew == -__builtin_inff()) ? 0.f : mnew;
    const float alpha = (m_run == -__builtin_inff()) ? 0.f : __expf(m_run - mnew);
    float p[16], rs = 0.f;
#pragma unroll
    for (int j = 0; j < 16; ++j) { p[j] = __expf(s[j] - mref); rs += p[j]; }
    rs += __shfl_xor(rs, 16);
    rs += __shfl_xor(rs, 32);
    l_run = l_run * alpha + rs;
    m_run = mnew;
#pragma unroll
    for (int mt = 0; mt < 4; ++mt)
#pragma unroll
      for (int i = 0; i < 4; ++i) acc[mt][i] *= alpha;

    // ---- P^T -> LDS as Pt[qr][key] ----
    ushort* pw = &Ps[w][l16 * 72 + quad * 4];
#pragma unroll
    for (int mt = 0; mt < 4; ++mt) {
      const uint pk0 = (uint)f2bf(p[mt * 4 + 0]) | ((uint)f2bf(p[mt * 4 + 1]) << 16);
      const uint pk1 = (uint)f2bf(p[mt * 4 + 2]) | ((uint)f2bf(p[mt * 4 + 3]) << 16);
      *(uint*)&pw[mt * 16] = pk0;
      *(uint*)&pw[mt * 16 + 2] = pk1;
    }

    // ---- O^T += V^T · P^T ----
#pragma unroll
    for (int kk = 0; kk < 2; ++kk) {
      const bf16x8 bP = *(const bf16x8*)&Ps[w][l16 * 72 + kk * 32 + quad * 8];
#pragma unroll
      for (int mt = 0; mt < 4; ++mt) {
        const int dd = mt * 16 + l16;
        const int cs = (((kk * 4 + quad) ^ (dd >> 3)) & 7) * 8;
        const bf16x8 aV = *(const bf16x8*)&Vs[dd * 64 + cs];
        acc[mt] = __builtin_amdgcn_mfma_f32_16x16x32_bf16(aV, bP, acc[mt], 0, 0, 0);
      }
    }

    __syncthreads();  // all waves done reading tile kt LDS

    // ---- write tile kt+1 regs -> LDS ----
    if (ktn < 40) {
#pragma unroll
      for (int c = 0; c < 2; ++c) {
        const int f = tid + c * 256;
        *(uint4*)&Ks[(f >> 3) * 72 + (f & 7) * 8] = kd[c];
        const int key = f >> 3, d0 = (f & 7) * 8;
        const int cb = (((key >> 3) ^ (f & 7)) & 7) * 8 + (key & 7);
        uint vv[4] = {vd[c].x, vd[c].y, vd[c].z, vd[c].w};
#pragma unroll
        for (int u = 0; u < 4; ++u) {
          Vs[(d0 + 2 * u) * 64 + cb] = (ushort)(vv[u] & 0xffffu);
          Vs[(d0 + 2 * u + 1) * 64 + cb] = (ushort)(vv[u] >> 16);
        }
      }
      if (ktn < 32) {
#pragma unroll
        for (int p = 0; p < 4; ++p) {
          const int f2 = tid * 4 + p * 1024, row = f2 >> 6, col = f2 & 63;
          float* bsw = &BiasS[row * 65 + col];
          bsw[0] = md[p].x ? -__builtin_inff() : rd[p].x;
          bsw[1] = md[p].y ? -__builtin_inff() : rd[p].y;
          bsw[2] = md[p].z ? -__builtin_inff() : rd[p].z;
          bsw[3] = md[p].w ? -__builtin_inff() : rd[p].w;
        }
      }
    }
    __syncthreads();  // tile kt+1 LDS ready
  }

  // ---- epilogue: y[b][t][h*64+d] bf16 ----
  const float inv = 1.f / l_run;
  ushort* yrow = yb + ((size_t)b * 2048 + qt * 64 + w * 16 + l16) * 768 + h * 64;
#pragma unroll
  for (int mt = 0; mt < 4; ++mt)
#pragma unroll
    for (int i = 0; i < 4; ++i)
      yrow[mt * 16 + quad * 4 + i] = f2bf(acc[mt][i] * inv);
}

// ---------------- launch ----------------
extern "C" void kernel_launch(void* const* d_in, const int* in_sizes, int n_in,
                              void* d_out, int out_size, void* d_ws, size_t ws_size,
                              hipStream_t stream) {
  const float* x = (const float*)d_in[0];
  const int* mask = (const int*)d_in[1];
  const float* relp = (const float*)d_in[2];
  const float* ref = (const float*)d_in[3];
  const float* Wq = (const float*)d_in[4];
  const float* bq = (const float*)d_in[5];
  const float* Wk = (const float*)d_in[6];
  const float* bk = (const float*)d_in[7];
  const float* Wv = (const float*)d_in[8];
  const float* bv = (const float*)d_in[9];
  const float* Wrk = (const float*)d_in[10];
  const float* brk = (const float*)d_in[11];
  const float* Wrv = (const float*)d_in[12];
  const float* brv = (const float*)d_in[13];
  const float* Wo = (const float*)d_in[14];
  const float* bo = (const float*)d_in[15];

  ushort* xb = (ushort*)d_ws;                 // 3,145,728
  ushort* refb = xb + 3145728;                // 786,432
  ushort* wb = refb + 786432;                 // 6 * 589,824  (q,k,v,rk,rv,o)
  ushort* qbuf = wb + 6 * 589824;             // 3,145,728   [b][h][t][d]
  ushort* kbuf = qbuf + 3145728;              // 3,932,160   [b][h][key][d], L=2560
  ushort* vbuf = kbuf + 3932160;              // 3,932,160
  ushort* ybuf = vbuf + 3932160;              // 3,145,728   [b][t][c]

  cast_all<<<7296, 256, 0, stream>>>(x, ref, Wq, Wk, Wv, Wrk, Wrv, Wo, xb);

  // fused QKV: W = Wq|Wk|Wv contiguous in wb
  gemm_fused<0><<<dim3(32, 18), 256, 0, stream>>>(
      xb, wb, bq, bk, bv, qbuf, kbuf, vbuf);
  // fused ref-KV: W = Wrk|Wrv contiguous
  gemm_fused<1><<<dim3(8, 12), 256, 0, stream>>>(
      refb, wb + (size_t)3 * 589824, brk, brv, nullptr, kbuf, vbuf, nullptr);

  attn<<<dim3(2, 32, 12), 256, 0, stream>>>(qbuf, kbuf, vbuf, mask, relp, ybuf);

  gemm_out<<<dim3(32, 6), 256, 0, stream>>>(
      ybuf, wb + (size_t)5 * 589824, bo, (float*)d_out);
}